// Round 11
// baseline (611.940 us; speedup 1.0000x reference)
//
#include <hip/hip_runtime.h>
#include <hip/hip_cooperative_groups.h>
#include <math.h>

namespace cg = cooperative_groups;

// Problem constants
#define BATCH   2
#define LSEQ    1024
#define DMODEL  1024
#define DSTATE  16
#define DCONV   4
#define DINNER  2048
#define NROWS   (BATCH * LSEQ)   // 2048

#define LCHUNK  32
#define NCHUNK  32

typedef short  bf16x8 __attribute__((ext_vector_type(8)));
typedef float  f32x4  __attribute__((ext_vector_type(4)));

__device__ __forceinline__ unsigned short f2bf(float f) {
  unsigned int u = __builtin_bit_cast(unsigned int, f);
  u = (u + 0x7fffu + ((u >> 16) & 1u)) >> 16;   // RNE
  return (unsigned short)u;
}
__device__ __forceinline__ float bf2f(unsigned short h) {
  return __builtin_bit_cast(float, (unsigned int)h << 16);
}

// ---------------------------------------------------------------------------
// Fused input conversion (R7-proven). 4 regions.
// ---------------------------------------------------------------------------
__device__ __forceinline__ void cvt_ew_body(const float* __restrict__ s,
                                            unsigned short* __restrict__ d,
                                            int blk, int tid) {
  int i = blk * 256 + tid;
  float4 v = ((const float4*)s)[i];
  ushort4 o;
  o.x = f2bf(v.x); o.y = f2bf(v.y); o.z = f2bf(v.z); o.w = f2bf(v.w);
  ((ushort4*)d)[i] = o;
}

__device__ __forceinline__ void cvt_tr_body(const float* __restrict__ s,
                                            unsigned short* __restrict__ d,
                                            int R, int C, int c0, int r0,
                                            int tid, float (*T)[33]) {
#pragma unroll
  for (int i = 0; i < 4; ++i) {
    int e = tid + i * 256;
    int r = e >> 5, c = e & 31;
    T[r][c] = s[(size_t)(r0 + r) * C + c0 + c];
  }
  __syncthreads();
#pragma unroll
  for (int i = 0; i < 4; ++i) {
    int e = tid + i * 256;
    int c = e >> 5, r = e & 31;
    d[(size_t)(c0 + c) * R + r0 + r] = f2bf(T[r][c]);
  }
}

__global__ __launch_bounds__(256) void cvt_all(
    const float* __restrict__ x, const float* __restrict__ w_in,
    const float* __restrict__ dt_w, const float* __restrict__ out_w,
    unsigned short* __restrict__ XB, unsigned short* __restrict__ WINB,
    unsigned short* __restrict__ DTWB, unsigned short* __restrict__ OWB) {
  __shared__ float T[32][33];
  const int bid = blockIdx.x;
  const int tid = threadIdx.x;
  if (bid < 2048) {
    cvt_ew_body(x, XB, bid, tid);
  } else if (bid < 6144) {
    int t = bid - 2048;
    cvt_tr_body(w_in, WINB, 1024, 4096, (t & 127) * 32, (t >> 7) * 32, tid, T);
  } else if (bid < 10240) {
    cvt_ew_body(dt_w, DTWB, bid - 6144, tid);
  } else {
    int t = bid - 10240;
    cvt_tr_body(out_w, OWB, 2048, 1024, (t & 31) * 32, (t >> 5) * 32, tid, T);
  }
}

// ---------------------------------------------------------------------------
// bf16 MFMA GEMM (NT), 512 threads, BM=128 x BN=128, BK=64 (R10 config —
// best measured). 8 waves: wave w -> rows (w>>2)*64, cols (w&3)*32; each wave
// 4x2 MFMAs of 16x16x32. LDS 32 KB, 2-barrier loop. Static XCD swizzle
// (gridDim.y==16). Split-K via gridDim.z.
// Epilogue modes: 0 = fp32 C1 (+z*zstride)       [unused now]
//                 1 = bf16 col<N1 -> C1 else C2  [in_proj u|res]
//                 2 = softplus(v+bias[col]) bf16 [dt_proj]
//                 3 = fp32 atomicAdd into C1     [out_proj split-K, C1 zeroed]
// ---------------------------------------------------------------------------
__global__ __launch_bounds__(512) void mfma_gemm_nt(
    const unsigned short* __restrict__ A, int lda,
    const unsigned short* __restrict__ Bt, int ldb,
    void* __restrict__ C1v, int ld1,
    void* __restrict__ C2v, int ld2, int N1,
    const float* __restrict__ bias,
    int KS, size_t zstride, int mode) {
  __shared__ unsigned short As[8 * 128 * 8];  // 16 KB [kc][row][8]
  __shared__ unsigned short Bs[8 * 128 * 8];  // 16 KB
  const int tid  = threadIdx.x;
  const int wave = tid >> 6;        // 0..7
  const int lane = tid & 63;
  const int linear = blockIdx.y * gridDim.x + blockIdx.x;
  const int xcd = linear & 7;
  const int pos = linear >> 3;
  const int row0 = (xcd * 2 + (pos & 1)) * 128;   // 16 M-panels
  const int col0 = (pos >> 1) * 128;
  const int wm0 = (wave >> 2) * 64;
  const int wn0 = (wave & 3) * 32;
  const int kb = blockIdx.z * KS;

  f32x4 acc[4][2];
#pragma unroll
  for (int i = 0; i < 4; ++i)
#pragma unroll
    for (int j = 0; j < 2; ++j) acc[i][j] = (f32x4){0.f, 0.f, 0.f, 0.f};

  const int lkc = lane >> 4, li = lane & 15;
  for (int k0 = kb; k0 < kb + KS; k0 += 64) {
#pragma unroll
    for (int it = 0; it < 2; ++it) {
      int s = it * 512 + tid;        // 0..1023 A slots (16B each)
      int kc = s >> 7, r = s & 127;
      __builtin_amdgcn_global_load_lds(
          (const __attribute__((address_space(1))) void*)(A + (size_t)(row0 + r) * lda + k0 + kc * 8),
          (__attribute__((address_space(3))) void*)(&As[s * 8]), 16, 0, 0);
    }
#pragma unroll
    for (int it = 0; it < 2; ++it) {
      int s = it * 512 + tid;        // 0..1023 B slots
      int kc = s >> 7, r = s & 127;
      __builtin_amdgcn_global_load_lds(
          (const __attribute__((address_space(1))) void*)(Bt + (size_t)(col0 + r) * ldb + k0 + kc * 8),
          (__attribute__((address_space(3))) void*)(&Bs[s * 8]), 16, 0, 0);
    }
    __syncthreads();
#pragma unroll
    for (int half = 0; half < 2; ++half) {
      bf16x8 af[4], bfr[2];
#pragma unroll
      for (int mt = 0; mt < 4; ++mt)
        af[mt] = *(const bf16x8*)&As[((half * 4 + lkc) * 128 + wm0 + mt * 16 + li) * 8];
#pragma unroll
      for (int nt = 0; nt < 2; ++nt)
        bfr[nt] = *(const bf16x8*)&Bs[((half * 4 + lkc) * 128 + wn0 + nt * 16 + li) * 8];
#pragma unroll
      for (int mt = 0; mt < 4; ++mt)
#pragma unroll
        for (int nt = 0; nt < 2; ++nt)
          acc[mt][nt] = __builtin_amdgcn_mfma_f32_16x16x32_bf16(
              af[mt], bfr[nt], acc[mt][nt], 0, 0, 0);
    }
    __syncthreads();
  }
  // C/D layout: col=lane&15, row=(lane>>4)*4+reg (m89-verified)
  const int lq = lane >> 4;
  const size_t zoff = (size_t)blockIdx.z * zstride;
#pragma unroll
  for (int mt = 0; mt < 4; ++mt) {
    int gm0 = row0 + wm0 + mt * 16 + lq * 4;
#pragma unroll
    for (int nt = 0; nt < 2; ++nt) {
      int gn = col0 + wn0 + nt * 16 + li;
      if (mode == 0) {
        float* C1 = (float*)C1v;
#pragma unroll
        for (int r = 0; r < 4; ++r)
          C1[zoff + (size_t)(gm0 + r) * ld1 + gn] = acc[mt][nt][r];
      } else if (mode == 1) {
        if (gn < N1) {
          unsigned short* C1 = (unsigned short*)C1v;
#pragma unroll
          for (int r = 0; r < 4; ++r)
            C1[(size_t)(gm0 + r) * ld1 + gn] = f2bf(acc[mt][nt][r]);
        } else {
          unsigned short* C2 = (unsigned short*)C2v;
#pragma unroll
          for (int r = 0; r < 4; ++r)
            C2[(size_t)(gm0 + r) * ld2 + gn - N1] = f2bf(acc[mt][nt][r]);
        }
      } else if (mode == 2) {  // softplus(v + bias[col]) -> bf16
        unsigned short* C1 = (unsigned short*)C1v;
        float bb = bias[gn];
#pragma unroll
        for (int r = 0; r < 4; ++r) {
          float v = acc[mt][nt][r] + bb;
          v = (v > 20.f) ? v : __logf(1.f + __expf(v));
          C1[(size_t)(gm0 + r) * ld1 + gn] = f2bf(v);
        }
      } else {  // mode 3: fp32 atomicAdd (C1 pre-zeroed by memset)
        float* C1 = (float*)C1v;
#pragma unroll
        for (int r = 0; r < 4; ++r)
          atomicAdd(&C1[(size_t)(gm0 + r) * ld1 + gn], acc[mt][nt][r]);
      }
    }
  }
}

// ---------------------------------------------------------------------------
// Fused depthwise conv(4)+SiLU + x_proj partial. Block (ks 0..7, rt 0..31):
// computes U for rows [rt*64, rt*64+64) x d [ks*256, ks*256+256) (each U
// element written exactly once), stages it in LDS, then accumulates the
// x_proj K-slice partial C[64][32] for that slab. Rolling 3-sample history
// handles the causal halo (row0 is a multiple of 64, so either the tile
// starts a batch (history=0) or all 3 halo rows are in-batch).
// ---------------------------------------------------------------------------
__global__ __launch_bounds__(256) void conv_xproj(
    const unsigned short* __restrict__ UPREB, const float* __restrict__ cw,
    const float* __restrict__ cb, const float* __restrict__ W,
    unsigned short* __restrict__ UB, float* __restrict__ XPART) {
  const int ks = blockIdx.x;        // 0..7 K-slices of 256
  const int rt = blockIdx.y;        // 0..31 row tiles of 64
  const int row0 = rt * 64;
  const int kbase = ks * 256;
  __shared__ unsigned short sU[64][256];  // 32 KB
  __shared__ float Bv[256 * 32];          // 32 KB
  const int tid = threadIdx.x;

  // stage W slice [kbase..kbase+256) x 32
  for (int i = tid; i < 256 * 32; i += 256)
    Bv[i] = W[(size_t)(kbase + (i >> 5)) * 32 + (i & 31)];

  // conv + silu for this slab (one d per thread, roll over 64 rows)
  {
    const int d = kbase + tid;
    const float w0 = cw[d * DCONV + 0], w1 = cw[d * DCONV + 1];
    const float w2 = cw[d * DCONV + 2], w3 = cw[d * DCONV + 3];
    const float bias = cb[d];
    float x0, x1, x2;
    if ((row0 & (LSEQ - 1)) == 0) {
      x0 = x1 = x2 = 0.f;
    } else {
      x0 = bf2f(UPREB[(size_t)(row0 - 3) * DINNER + d]);
      x1 = bf2f(UPREB[(size_t)(row0 - 2) * DINNER + d]);
      x2 = bf2f(UPREB[(size_t)(row0 - 1) * DINNER + d]);
    }
    for (int r = 0; r < 64; ++r) {
      float x3 = bf2f(UPREB[(size_t)(row0 + r) * DINNER + d]);
      float a = bias + x0 * w0 + x1 * w1 + x2 * w2 + x3 * w3;
      float u = a / (1.f + __expf(-a));
      unsigned short ub = f2bf(u);
      sU[r][tid] = ub;
      UB[(size_t)(row0 + r) * DINNER + d] = ub;
      x0 = x1; x1 = x2; x2 = x3;
    }
  }
  __syncthreads();

  // x_proj partial: C[64][32] = sU[64][256] @ W[256][32]
  const int col = tid & 31, rg = tid >> 5;   // 8 row-groups x 8 rows
  float acc[8] = {};
  for (int k = 0; k < 256; k += 2) {
    float b0 = Bv[k * 32 + col], b1 = Bv[(k + 1) * 32 + col];
#pragma unroll
    for (int rr = 0; rr < 8; ++rr) {
      ushort2 uv = *(const ushort2*)&sU[rg * 8 + rr][k];
      acc[rr] += bf2f(uv.x) * b0 + bf2f(uv.y) * b1;
    }
  }
#pragma unroll
  for (int rr = 0; rr < 8; ++rr)
    XPART[(size_t)ks * NROWS * 32 + (size_t)(row0 + rg * 8 + rr) * 32 + col] = acc[rr];
}

__global__ __launch_bounds__(256) void xproj_reduce(
    const float* __restrict__ XPART, float* __restrict__ BC) {
  int i = blockIdx.x * 256 + threadIdx.x;
  float s = 0.f;
#pragma unroll
  for (int ks = 0; ks < 8; ++ks) s += XPART[(size_t)ks * NROWS * 32 + i];
  BC[i] = s;
}

// ---------------------------------------------------------------------------
// Cooperative fused scan: phase1 (local chunk scan, publish P/H, stash
// delta/u in LDS) -> grid.sync -> phase2 (serial inter-chunk prefix, 256 of
// 512 blocks) -> grid.sync -> phase3 (rescan from incoming state, gate, YB).
// 512 blocks x 256 thr, LDS 36 KB -> 2 blocks/CU co-resident.
// ---------------------------------------------------------------------------
__global__ __launch_bounds__(256) void scan_coop(
    const unsigned short* __restrict__ DELTAB, const unsigned short* __restrict__ UB,
    const float* __restrict__ BC, const float* __restrict__ A_log,
    const float* __restrict__ D_param, const unsigned short* __restrict__ RESB,
    unsigned short* __restrict__ YB,
    float* __restrict__ PBUF, float* __restrict__ HBUF) {
  cg::grid_group grid = cg::this_grid();
  const int bx = blockIdx.x;
  const int tid = threadIdx.x;
  const int b = bx >> 8;
  const int c = (bx >> 3) & (NCHUNK - 1);
  const int d = ((bx & 7) << 8) + tid;
  const int l0 = c * LCHUNK;
  __shared__ float sBC[LCHUNK * 32];            // 4 KB (B | C per step)
  __shared__ unsigned short sDU[LCHUNK * 256 * 2];  // 32 KB (delta,u per step,d)

#pragma unroll
  for (int i = 0; i < 4; ++i) {
    int e = tid + i * 256;
    sBC[e] = BC[((size_t)(b * LSEQ + l0 + (e >> 5))) * 32 + (e & 31)];
  }
  float Avv[DSTATE];
#pragma unroll
  for (int n = 0; n < DSTATE; ++n) Avv[n] = -__expf(A_log[d * DSTATE + n]);
  float h[DSTATE], P[DSTATE];
#pragma unroll
  for (int n = 0; n < DSTATE; ++n) { h[n] = 0.f; P[n] = 1.f; }
  __syncthreads();

  // phase 1: local scan
  for (int lc = 0; lc < LCHUNK; ++lc) {
    size_t off = ((size_t)(b * LSEQ + l0 + lc)) * DINNER + d;
    unsigned short dh = DELTAB[off], uh = UB[off];
    ushort2 duv; duv.x = dh; duv.y = uh;
    ((ushort2*)sDU)[lc * 256 + tid] = duv;
    float delta = bf2f(dh);
    float du = delta * bf2f(uh);
#pragma unroll
    for (int n = 0; n < DSTATE; ++n) {
      float dA = __expf(delta * Avv[n]);
      P[n] *= dA;
      h[n] = dA * h[n] + du * sBC[lc * 32 + n];
    }
  }
  size_t base = ((size_t)(b * NCHUNK + c)) * DSTATE * DINNER + d;
#pragma unroll
  for (int n = 0; n < DSTATE; ++n) {
    PBUF[base + (size_t)n * DINNER] = P[n];
    HBUF[base + (size_t)n * DINNER] = h[n];
  }
  __threadfence();
  grid.sync();

  // phase 2: inter-chunk prefix (blocks 0..255); HBUF[c] := incoming state
  if (bx < 256) {
    const int b2 = bx >> 7;
    const int n2 = (bx >> 3) & (DSTATE - 1);
    const int d2 = ((bx & 7) << 8) + tid;
    float hh = 0.f;
    for (int cc = 0; cc < NCHUNK; ++cc) {
      size_t idx = (((size_t)(b2 * NCHUNK + cc)) * DSTATE + n2) * DINNER + d2;
      float p = PBUF[idx];
      float hl = HBUF[idx];
      HBUF[idx] = hh;
      hh = p * hh + hl;
    }
  }
  __threadfence();
  grid.sync();
  __threadfence();

  // phase 3: rescan from incoming state, gate silu(res), emit bf16 Y
#pragma unroll
  for (int n = 0; n < DSTATE; ++n) h[n] = HBUF[base + (size_t)n * DINNER];
  const float Dp = D_param[d];
  for (int lc = 0; lc < LCHUNK; ++lc) {
    ushort2 duv = ((ushort2*)sDU)[lc * 256 + tid];
    float delta = bf2f(duv.x);
    float uu = bf2f(duv.y);
    float du = delta * uu;
    float y = 0.f;
#pragma unroll
    for (int n = 0; n < DSTATE; ++n) {
      float dA = __expf(delta * Avv[n]);
      h[n] = dA * h[n] + du * sBC[lc * 32 + n];
      y += h[n] * sBC[lc * 32 + 16 + n];
    }
    y += uu * Dp;
    size_t off = ((size_t)(b * LSEQ + l0 + lc)) * DINNER + d;
    float r = bf2f(RESB[off]);
    YB[off] = f2bf(y * (r / (1.f + __expf(-r))));
  }
}

// ---------------------------------------------------------------------------
extern "C" void kernel_launch(void* const* d_in, const int* in_sizes, int n_in,
                              void* d_out, int out_size, void* d_ws, size_t ws_size,
                              hipStream_t stream) {
  const float* x       = (const float*)d_in[0];
  const float* w_in    = (const float*)d_in[1];
  const float* conv_w  = (const float*)d_in[2];
  const float* conv_b  = (const float*)d_in[3];
  const float* xproj_w = (const float*)d_in[4];
  const float* dt_w    = (const float*)d_in[5];
  const float* dt_b    = (const float*)d_in[6];
  const float* A_log   = (const float*)d_in[7];
  const float* D_par   = (const float*)d_in[8];
  const float* out_w   = (const float*)d_in[9];
  float* out = (float*)d_out;

  char* ws = (char*)d_ws;
  const size_t MB = 1024 * 1024;
  // bf16 activation buffers
  unsigned short* UPREB  = (unsigned short*)(ws + 0 * MB);   // 8 MB (dead after conv_xproj)
  unsigned short* RESB   = (unsigned short*)(ws + 8 * MB);   // 8 MB (dead after scan)
  unsigned short* UB     = (unsigned short*)(ws + 16 * MB);  // 8 MB
  unsigned short* DELTAB = (unsigned short*)(ws + 24 * MB);  // 8 MB
  unsigned short* YB     = (unsigned short*)(ws + 32 * MB);  // 8 MB
  unsigned short* XB     = (unsigned short*)(ws + 40 * MB);  // 4 MB (dead after in_proj)
  unsigned short* WINB   = (unsigned short*)(ws + 44 * MB);  // 8 MB (dead after in_proj)
  unsigned short* DTWB   = (unsigned short*)(ws + 52 * MB);  // 8 MB (dead after dt_proj)
  unsigned short* OWB    = (unsigned short*)(ws + 60 * MB);  // 4 MB (live to end)
  // overlays (first written strictly after underlying buffer dies)
  float* PBUF  = (float*)(ws + 0 * MB);                 // 8 MB over UPREB (w: scan)
  float* HBUF  = (float*)(ws + 40 * MB);                // 8 MB over XB+WINB[0:4] (w: scan)
  float* BCb   = (float*)(ws + 48 * MB);                // 256 KB over WINB[4:]
  float* XPART = (float*)(ws + 48 * MB + 512 * 1024);   // 2 MB over WINB[4:]
  // footprint: 64 MB

  // zero the atomic-accumulated output (poisoned 0xAA before every launch)
  hipMemsetAsync(d_out, 0, (size_t)out_size * sizeof(float), stream);
  // input conversions
  cvt_all<<<dim3(12288), dim3(256), 0, stream>>>(x, w_in, dt_w, out_w, XB, WINB, DTWB, OWB);
  // in_proj: XB(2048x1024) x WINB(4096x1024)^T -> UPREB | RESB bf16
  mfma_gemm_nt<<<dim3(2 * DINNER / 128, NROWS / 128, 1), dim3(512), 0, stream>>>(
      XB, DMODEL, WINB, DMODEL, UPREB, DINNER, RESB, DINNER, DINNER,
      nullptr, DMODEL, 0, 1);
  // fused conv+silu+x_proj partial -> UB, XPART
  conv_xproj<<<dim3(8, NROWS / 64), dim3(256), 0, stream>>>(
      UPREB, conv_w, conv_b, xproj_w, UB, XPART);
  xproj_reduce<<<dim3(NROWS * 32 / 256), dim3(256), 0, stream>>>(XPART, BCb);
  // dt_proj: UB x DTWB^T, softplus(+dt_b) epilogue -> DELTAB bf16
  mfma_gemm_nt<<<dim3(DINNER / 128, NROWS / 128, 1), dim3(512), 0, stream>>>(
      UB, DINNER, DTWB, DINNER, DELTAB, DINNER, nullptr, 0, DINNER,
      dt_b, DINNER, 0, 2);
  // fused cooperative scan
  {
    void* args[] = {(void*)&DELTAB, (void*)&UB, (void*)&BCb, (void*)&A_log,
                    (void*)&D_par, (void*)&RESB, (void*)&YB,
                    (void*)&PBUF, (void*)&HBUF};
    hipLaunchCooperativeKernel((void*)scan_coop, dim3(512), dim3(256),
                               args, 0, stream);
  }
  // out_proj: YB(2048x2048) x OWB(1024x2048)^T, split-K=2 atomicAdd -> out
  mfma_gemm_nt<<<dim3(DMODEL / 128, NROWS / 128, 2), dim3(512), 0, stream>>>(
      YB, DINNER, OWB, DINNER, out, DMODEL, nullptr, 0, DMODEL,
      nullptr, DINNER / 2, 0, 3);
}

// Round 12
// 331.021 us; speedup vs baseline: 1.8486x; 1.8486x over previous
//
#include <hip/hip_runtime.h>
#include <math.h>

// Problem constants
#define BATCH   2
#define LSEQ    1024
#define DMODEL  1024
#define DSTATE  16
#define DCONV   4
#define DINNER  2048
#define NROWS   (BATCH * LSEQ)   // 2048

#define LCHUNK  32
#define NCHUNK  32

typedef short  bf16x8 __attribute__((ext_vector_type(8)));
typedef float  f32x4  __attribute__((ext_vector_type(4)));

__device__ __forceinline__ unsigned short f2bf(float f) {
  unsigned int u = __builtin_bit_cast(unsigned int, f);
  u = (u + 0x7fffu + ((u >> 16) & 1u)) >> 16;   // RNE
  return (unsigned short)u;
}
__device__ __forceinline__ float bf2f(unsigned short h) {
  return __builtin_bit_cast(float, (unsigned int)h << 16);
}

// ---------------------------------------------------------------------------
// Fused input conversion (R7-proven). 4 regions.
// ---------------------------------------------------------------------------
__device__ __forceinline__ void cvt_ew_body(const float* __restrict__ s,
                                            unsigned short* __restrict__ d,
                                            int blk, int tid) {
  int i = blk * 256 + tid;
  float4 v = ((const float4*)s)[i];
  ushort4 o;
  o.x = f2bf(v.x); o.y = f2bf(v.y); o.z = f2bf(v.z); o.w = f2bf(v.w);
  ((ushort4*)d)[i] = o;
}

__device__ __forceinline__ void cvt_tr_body(const float* __restrict__ s,
                                            unsigned short* __restrict__ d,
                                            int R, int C, int c0, int r0,
                                            int tid, float (*T)[33]) {
#pragma unroll
  for (int i = 0; i < 4; ++i) {
    int e = tid + i * 256;
    int r = e >> 5, c = e & 31;
    T[r][c] = s[(size_t)(r0 + r) * C + c0 + c];
  }
  __syncthreads();
#pragma unroll
  for (int i = 0; i < 4; ++i) {
    int e = tid + i * 256;
    int c = e >> 5, r = e & 31;
    d[(size_t)(c0 + c) * R + r0 + r] = f2bf(T[r][c]);
  }
}

__global__ __launch_bounds__(256) void cvt_all(
    const float* __restrict__ x, const float* __restrict__ w_in,
    const float* __restrict__ dt_w, const float* __restrict__ out_w,
    unsigned short* __restrict__ XB, unsigned short* __restrict__ WINB,
    unsigned short* __restrict__ DTWB, unsigned short* __restrict__ OWB) {
  __shared__ float T[32][33];
  const int bid = blockIdx.x;
  const int tid = threadIdx.x;
  if (bid < 2048) {
    cvt_ew_body(x, XB, bid, tid);
  } else if (bid < 6144) {
    int t = bid - 2048;
    cvt_tr_body(w_in, WINB, 1024, 4096, (t & 127) * 32, (t >> 7) * 32, tid, T);
  } else if (bid < 10240) {
    cvt_ew_body(dt_w, DTWB, bid - 6144, tid);
  } else {
    int t = bid - 10240;
    cvt_tr_body(out_w, OWB, 2048, 1024, (t & 31) * 32, (t >> 5) * 32, tid, T);
  }
}

// ---------------------------------------------------------------------------
// bf16 MFMA GEMM (NT), 512 threads, BM=128 x BN=128, BK=64 (R10 config —
// best measured). 8 waves: wave w -> rows (w>>2)*64, cols (w&3)*32; each wave
// 4x2 MFMAs of 16x16x32. LDS 32 KB, 2-barrier loop. Static XCD swizzle
// (gridDim.y==16). Split-K via gridDim.z.
// Epilogue modes: 1 = bf16 col<N1 -> C1 else C2  [in_proj u|res]
//                 2 = softplus(v+bias[col]) bf16 [dt_proj]
//                 3 = fp32 atomicAdd into C1     [out_proj split-K, C1 zeroed]
// NOTE (R8/R11 lesson): NO inter-block coordination inside kernels — queues
// and grid.sync cost 100+ µs on 8 non-coherent XCDs. Launches are the cheap
// sync primitive. One-shot epilogue atomics (mode 3) are fine.
// ---------------------------------------------------------------------------
__global__ __launch_bounds__(512) void mfma_gemm_nt(
    const unsigned short* __restrict__ A, int lda,
    const unsigned short* __restrict__ Bt, int ldb,
    void* __restrict__ C1v, int ld1,
    void* __restrict__ C2v, int ld2, int N1,
    const float* __restrict__ bias,
    int KS, int mode) {
  __shared__ unsigned short As[8 * 128 * 8];  // 16 KB [kc][row][8]
  __shared__ unsigned short Bs[8 * 128 * 8];  // 16 KB
  const int tid  = threadIdx.x;
  const int wave = tid >> 6;        // 0..7
  const int lane = tid & 63;
  const int linear = blockIdx.y * gridDim.x + blockIdx.x;
  const int xcd = linear & 7;
  const int pos = linear >> 3;
  const int row0 = (xcd * 2 + (pos & 1)) * 128;   // 16 M-panels
  const int col0 = (pos >> 1) * 128;
  const int wm0 = (wave >> 2) * 64;
  const int wn0 = (wave & 3) * 32;
  const int kb = blockIdx.z * KS;

  f32x4 acc[4][2];
#pragma unroll
  for (int i = 0; i < 4; ++i)
#pragma unroll
    for (int j = 0; j < 2; ++j) acc[i][j] = (f32x4){0.f, 0.f, 0.f, 0.f};

  const int lkc = lane >> 4, li = lane & 15;
  for (int k0 = kb; k0 < kb + KS; k0 += 64) {
#pragma unroll
    for (int it = 0; it < 2; ++it) {
      int s = it * 512 + tid;        // 0..1023 A slots (16B each)
      int kc = s >> 7, r = s & 127;
      __builtin_amdgcn_global_load_lds(
          (const __attribute__((address_space(1))) void*)(A + (size_t)(row0 + r) * lda + k0 + kc * 8),
          (__attribute__((address_space(3))) void*)(&As[s * 8]), 16, 0, 0);
    }
#pragma unroll
    for (int it = 0; it < 2; ++it) {
      int s = it * 512 + tid;        // 0..1023 B slots
      int kc = s >> 7, r = s & 127;
      __builtin_amdgcn_global_load_lds(
          (const __attribute__((address_space(1))) void*)(Bt + (size_t)(col0 + r) * ldb + k0 + kc * 8),
          (__attribute__((address_space(3))) void*)(&Bs[s * 8]), 16, 0, 0);
    }
    __syncthreads();
#pragma unroll
    for (int half = 0; half < 2; ++half) {
      bf16x8 af[4], bfr[2];
#pragma unroll
      for (int mt = 0; mt < 4; ++mt)
        af[mt] = *(const bf16x8*)&As[((half * 4 + lkc) * 128 + wm0 + mt * 16 + li) * 8];
#pragma unroll
      for (int nt = 0; nt < 2; ++nt)
        bfr[nt] = *(const bf16x8*)&Bs[((half * 4 + lkc) * 128 + wn0 + nt * 16 + li) * 8];
#pragma unroll
      for (int mt = 0; mt < 4; ++mt)
#pragma unroll
        for (int nt = 0; nt < 2; ++nt)
          acc[mt][nt] = __builtin_amdgcn_mfma_f32_16x16x32_bf16(
              af[mt], bfr[nt], acc[mt][nt], 0, 0, 0);
    }
    __syncthreads();
  }
  // C/D layout: col=lane&15, row=(lane>>4)*4+reg (m89-verified)
  const int lq = lane >> 4;
#pragma unroll
  for (int mt = 0; mt < 4; ++mt) {
    int gm0 = row0 + wm0 + mt * 16 + lq * 4;
#pragma unroll
    for (int nt = 0; nt < 2; ++nt) {
      int gn = col0 + wn0 + nt * 16 + li;
      if (mode == 1) {
        if (gn < N1) {
          unsigned short* C1 = (unsigned short*)C1v;
#pragma unroll
          for (int r = 0; r < 4; ++r)
            C1[(size_t)(gm0 + r) * ld1 + gn] = f2bf(acc[mt][nt][r]);
        } else {
          unsigned short* C2 = (unsigned short*)C2v;
#pragma unroll
          for (int r = 0; r < 4; ++r)
            C2[(size_t)(gm0 + r) * ld2 + gn - N1] = f2bf(acc[mt][nt][r]);
        }
      } else if (mode == 2) {  // softplus(v + bias[col]) -> bf16
        unsigned short* C1 = (unsigned short*)C1v;
        float bb = bias[gn];
#pragma unroll
        for (int r = 0; r < 4; ++r) {
          float v = acc[mt][nt][r] + bb;
          v = (v > 20.f) ? v : __logf(1.f + __expf(v));
          C1[(size_t)(gm0 + r) * ld1 + gn] = f2bf(v);
        }
      } else {  // mode 3: fp32 atomicAdd (C1 pre-zeroed by memset)
        float* C1 = (float*)C1v;
#pragma unroll
        for (int r = 0; r < 4; ++r)
          atomicAdd(&C1[(size_t)(gm0 + r) * ld1 + gn], acc[mt][nt][r]);
      }
    }
  }
}

// ---------------------------------------------------------------------------
// Fused depthwise conv(4)+SiLU + x_proj partial (R11-proven). Block (ks, rt):
// U for rows [rt*64,+64) x d [ks*256,+256), stage in LDS, write UB once,
// then accumulate x_proj K-slice partial C[64][32].
// ---------------------------------------------------------------------------
__global__ __launch_bounds__(256) void conv_xproj(
    const unsigned short* __restrict__ UPREB, const float* __restrict__ cw,
    const float* __restrict__ cb, const float* __restrict__ W,
    unsigned short* __restrict__ UB, float* __restrict__ XPART) {
  const int ks = blockIdx.x;        // 0..7
  const int rt = blockIdx.y;        // 0..31
  const int row0 = rt * 64;
  const int kbase = ks * 256;
  __shared__ unsigned short sU[64][256];  // 32 KB
  __shared__ float Bv[256 * 32];          // 32 KB
  const int tid = threadIdx.x;

  for (int i = tid; i < 256 * 32; i += 256)
    Bv[i] = W[(size_t)(kbase + (i >> 5)) * 32 + (i & 31)];

  {
    const int d = kbase + tid;
    const float w0 = cw[d * DCONV + 0], w1 = cw[d * DCONV + 1];
    const float w2 = cw[d * DCONV + 2], w3 = cw[d * DCONV + 3];
    const float bias = cb[d];
    float x0, x1, x2;
    if ((row0 & (LSEQ - 1)) == 0) {
      x0 = x1 = x2 = 0.f;
    } else {
      x0 = bf2f(UPREB[(size_t)(row0 - 3) * DINNER + d]);
      x1 = bf2f(UPREB[(size_t)(row0 - 2) * DINNER + d]);
      x2 = bf2f(UPREB[(size_t)(row0 - 1) * DINNER + d]);
    }
    for (int r = 0; r < 64; ++r) {
      float x3 = bf2f(UPREB[(size_t)(row0 + r) * DINNER + d]);
      float a = bias + x0 * w0 + x1 * w1 + x2 * w2 + x3 * w3;
      float u = a / (1.f + __expf(-a));
      unsigned short ub = f2bf(u);
      sU[r][tid] = ub;
      UB[(size_t)(row0 + r) * DINNER + d] = ub;
      x0 = x1; x1 = x2; x2 = x3;
    }
  }
  __syncthreads();

  const int col = tid & 31, rg = tid >> 5;
  float acc[8] = {};
  for (int k = 0; k < 256; k += 2) {
    float b0 = Bv[k * 32 + col], b1 = Bv[(k + 1) * 32 + col];
#pragma unroll
    for (int rr = 0; rr < 8; ++rr) {
      ushort2 uv = *(const ushort2*)&sU[rg * 8 + rr][k];
      acc[rr] += bf2f(uv.x) * b0 + bf2f(uv.y) * b1;
    }
  }
#pragma unroll
  for (int rr = 0; rr < 8; ++rr)
    XPART[(size_t)ks * NROWS * 32 + (size_t)(row0 + rg * 8 + rr) * 32 + col] = acc[rr];
}

__global__ __launch_bounds__(256) void xproj_reduce(
    const float* __restrict__ XPART, float* __restrict__ BC) {
  int i = blockIdx.x * 256 + threadIdx.x;
  float s = 0.f;
#pragma unroll
  for (int ks = 0; ks < 8; ++ks) s += XPART[(size_t)ks * NROWS * 32 + i];
  BC[i] = s;
}

// ---------------------------------------------------------------------------
// Scan pass 1 (R10-proven): per-chunk decay product P[n], local h[n] (h0=0).
// ---------------------------------------------------------------------------
__global__ __launch_bounds__(256) void scan_pass1(
    const unsigned short* __restrict__ DELTAB, const unsigned short* __restrict__ UB,
    const float* __restrict__ BC, const float* __restrict__ A_log,
    float* __restrict__ PBUF, float* __restrict__ HBUF) {
  const int bx = blockIdx.x;
  const int b = bx >> 8;
  const int c = (bx >> 3) & (NCHUNK - 1);
  const int d = ((bx & 7) << 8) + threadIdx.x;
  const int l0 = c * LCHUNK;
  __shared__ float sB[LCHUNK * DSTATE];
#pragma unroll
  for (int i = 0; i < 2; ++i) {
    int e = threadIdx.x + i * 256;
    sB[e] = BC[((size_t)(b * LSEQ + l0 + (e >> 4))) * 32 + (e & 15)];
  }
  float Avv[DSTATE];
#pragma unroll
  for (int n = 0; n < DSTATE; ++n) Avv[n] = -__expf(A_log[d * DSTATE + n]);
  float h[DSTATE], P[DSTATE];
#pragma unroll
  for (int n = 0; n < DSTATE; ++n) { h[n] = 0.f; P[n] = 1.f; }
  __syncthreads();
  for (int lc = 0; lc < LCHUNK; ++lc) {
    size_t off = ((size_t)(b * LSEQ + l0 + lc)) * DINNER + d;
    float delta = bf2f(DELTAB[off]);
    float du = delta * bf2f(UB[off]);
#pragma unroll
    for (int n = 0; n < DSTATE; ++n) {
      float dA = __expf(delta * Avv[n]);
      P[n] *= dA;
      h[n] = dA * h[n] + du * sB[lc * DSTATE + n];
    }
  }
  size_t base = ((size_t)(b * NCHUNK + c)) * DSTATE * DINNER + d;
#pragma unroll
  for (int n = 0; n < DSTATE; ++n) {
    PBUF[base + (size_t)n * DINNER] = P[n];
    HBUF[base + (size_t)n * DINNER] = h[n];
  }
}

// ---------------------------------------------------------------------------
// Scan combine: sequential prefix across 32 chunks per (b,n,d).
// ---------------------------------------------------------------------------
__global__ __launch_bounds__(256) void scan_combine(
    const float* __restrict__ PBUF, float* __restrict__ HBUF) {
  const int bx = blockIdx.x;
  const int b = bx >> 7;
  const int n = (bx >> 3) & (DSTATE - 1);
  const int d = ((bx & 7) << 8) + threadIdx.x;
  float h = 0.f;
  for (int c = 0; c < NCHUNK; ++c) {
    size_t idx = (((size_t)(b * NCHUNK + c)) * DSTATE + n) * DINNER + d;
    float p = PBUF[idx];
    float hl = HBUF[idx];
    HBUF[idx] = h;
    h = p * h + hl;
  }
}

// ---------------------------------------------------------------------------
// Scan pass 2: rescan from incoming state; y = C.h + u*D, gate silu(res),
// emit bf16 Y.
// ---------------------------------------------------------------------------
__global__ __launch_bounds__(256) void scan_pass2(
    const unsigned short* __restrict__ DELTAB, const unsigned short* __restrict__ UB,
    const float* __restrict__ BC, const float* __restrict__ HBUF,
    const float* __restrict__ A_log, const float* __restrict__ D_param,
    const unsigned short* __restrict__ RESB, unsigned short* __restrict__ YB) {
  const int bx = blockIdx.x;
  const int b = bx >> 8;
  const int c = (bx >> 3) & (NCHUNK - 1);
  const int d = ((bx & 7) << 8) + threadIdx.x;
  const int l0 = c * LCHUNK;
  __shared__ float sBC[LCHUNK * 32];
#pragma unroll
  for (int i = 0; i < 4; ++i) {
    int e = threadIdx.x + i * 256;
    sBC[e] = BC[((size_t)(b * LSEQ + l0 + (e >> 5))) * 32 + (e & 31)];
  }
  float Avv[DSTATE];
#pragma unroll
  for (int n = 0; n < DSTATE; ++n) Avv[n] = -__expf(A_log[d * DSTATE + n]);
  const float Dp = D_param[d];
  float h[DSTATE];
  size_t base = ((size_t)(b * NCHUNK + c)) * DSTATE * DINNER + d;
#pragma unroll
  for (int n = 0; n < DSTATE; ++n) h[n] = HBUF[base + (size_t)n * DINNER];
  __syncthreads();
  for (int lc = 0; lc < LCHUNK; ++lc) {
    size_t off = ((size_t)(b * LSEQ + l0 + lc)) * DINNER + d;
    float delta = bf2f(DELTAB[off]);
    float uu = bf2f(UB[off]);
    float du = delta * uu;
    float y = 0.f;
#pragma unroll
    for (int n = 0; n < DSTATE; ++n) {
      float dA = __expf(delta * Avv[n]);
      h[n] = dA * h[n] + du * sBC[lc * 32 + n];
      y += h[n] * sBC[lc * 32 + 16 + n];
    }
    y += uu * Dp;
    float r = bf2f(RESB[off]);
    YB[off] = f2bf(y * (r / (1.f + __expf(-r))));
  }
}

// ---------------------------------------------------------------------------
extern "C" void kernel_launch(void* const* d_in, const int* in_sizes, int n_in,
                              void* d_out, int out_size, void* d_ws, size_t ws_size,
                              hipStream_t stream) {
  const float* x       = (const float*)d_in[0];
  const float* w_in    = (const float*)d_in[1];
  const float* conv_w  = (const float*)d_in[2];
  const float* conv_b  = (const float*)d_in[3];
  const float* xproj_w = (const float*)d_in[4];
  const float* dt_w    = (const float*)d_in[5];
  const float* dt_b    = (const float*)d_in[6];
  const float* A_log   = (const float*)d_in[7];
  const float* D_par   = (const float*)d_in[8];
  const float* out_w   = (const float*)d_in[9];
  float* out = (float*)d_out;

  char* ws = (char*)d_ws;
  const size_t MB = 1024 * 1024;
  // bf16 activation buffers
  unsigned short* UPREB  = (unsigned short*)(ws + 0 * MB);   // 8 MB (dead after conv_xproj)
  unsigned short* RESB   = (unsigned short*)(ws + 8 * MB);   // 8 MB (dead after scan)
  unsigned short* UB     = (unsigned short*)(ws + 16 * MB);  // 8 MB
  unsigned short* DELTAB = (unsigned short*)(ws + 24 * MB);  // 8 MB
  unsigned short* YB     = (unsigned short*)(ws + 32 * MB);  // 8 MB
  unsigned short* XB     = (unsigned short*)(ws + 40 * MB);  // 4 MB (dead after in_proj)
  unsigned short* WINB   = (unsigned short*)(ws + 44 * MB);  // 8 MB (dead after in_proj)
  unsigned short* DTWB   = (unsigned short*)(ws + 52 * MB);  // 8 MB (dead after dt_proj)
  unsigned short* OWB    = (unsigned short*)(ws + 60 * MB);  // 4 MB (live to end)
  // overlays (first written strictly after underlying buffer dies)
  float* PBUF  = (float*)(ws + 0 * MB);                 // 8 MB over UPREB (w: pass1)
  float* HBUF  = (float*)(ws + 40 * MB);                // 8 MB over XB+WINB[0:4] (w: pass1)
  float* BCb   = (float*)(ws + 48 * MB);                // 256 KB over WINB[4:]
  float* XPART = (float*)(ws + 48 * MB + 512 * 1024);   // 2 MB over WINB[4:]
  // footprint: 64 MB

  // zero the atomic-accumulated output (harness poisons d_out each launch)
  hipMemsetAsync(d_out, 0, (size_t)out_size * sizeof(float), stream);
  // input conversions
  cvt_all<<<dim3(12288), dim3(256), 0, stream>>>(x, w_in, dt_w, out_w, XB, WINB, DTWB, OWB);
  // in_proj: XB(2048x1024) x WINB(4096x1024)^T -> UPREB | RESB bf16
  mfma_gemm_nt<<<dim3(2 * DINNER / 128, NROWS / 128, 1), dim3(512), 0, stream>>>(
      XB, DMODEL, WINB, DMODEL, UPREB, DINNER, RESB, DINNER, DINNER,
      nullptr, DMODEL, 1);
  // fused conv+silu+x_proj partial -> UB, XPART
  conv_xproj<<<dim3(8, NROWS / 64), dim3(256), 0, stream>>>(
      UPREB, conv_w, conv_b, xproj_w, UB, XPART);
  xproj_reduce<<<dim3(NROWS * 32 / 256), dim3(256), 0, stream>>>(XPART, BCb);
  // dt_proj: UB x DTWB^T, softplus(+dt_b) epilogue -> DELTAB bf16
  mfma_gemm_nt<<<dim3(DINNER / 128, NROWS / 128, 1), dim3(512), 0, stream>>>(
      UB, DINNER, DTWB, DINNER, DELTAB, DINNER, nullptr, 0, DINNER,
      dt_b, DINNER, 2);
  // chunked selective scan (3 dispatches — launches ARE the sync primitive)
  scan_pass1<<<dim3(BATCH * NCHUNK * (DINNER / 256)), dim3(256), 0, stream>>>(
      DELTAB, UB, BCb, A_log, PBUF, HBUF);
  scan_combine<<<dim3(BATCH * DSTATE * (DINNER / 256)), dim3(256), 0, stream>>>(PBUF, HBUF);
  scan_pass2<<<dim3(BATCH * NCHUNK * (DINNER / 256)), dim3(256), 0, stream>>>(
      DELTAB, UB, BCb, HBUF, A_log, D_par, RESB, YB);
  // out_proj: YB(2048x2048) x OWB(1024x2048)^T, split-K=2 atomicAdd -> out
  mfma_gemm_nt<<<dim3(DMODEL / 128, NROWS / 128, 2), dim3(512), 0, stream>>>(
      YB, DINNER, OWB, DINNER, out, DMODEL, nullptr, 0, DMODEL,
      nullptr, DINNER / 2, 3);
}

// Round 13
// 327.360 us; speedup vs baseline: 1.8693x; 1.0112x over previous
//
#include <hip/hip_runtime.h>
#include <math.h>

// Problem constants
#define BATCH   2
#define LSEQ    1024
#define DMODEL  1024
#define DSTATE  16
#define DCONV   4
#define DINNER  2048
#define NROWS   (BATCH * LSEQ)   // 2048

#define LCHUNK  32
#define NCHUNK  32

typedef short  bf16x8 __attribute__((ext_vector_type(8)));
typedef float  f32x4  __attribute__((ext_vector_type(4)));

__device__ __forceinline__ unsigned short f2bf(float f) {
  unsigned int u = __builtin_bit_cast(unsigned int, f);
  u = (u + 0x7fffu + ((u >> 16) & 1u)) >> 16;   // RNE
  return (unsigned short)u;
}
__device__ __forceinline__ float bf2f(unsigned short h) {
  return __builtin_bit_cast(float, (unsigned int)h << 16);
}

// ---------------------------------------------------------------------------
// Fused input conversion + d_out zeroing. 5 regions:
//  [0,2048)       x      ew (2M elems)
//  [2048,6144)    w_in   transpose 1024x4096 -> 4096x1024
//  [6144,10240)   dt_w   ew (4M elems)
//  [10240,12288)  out_w  transpose 2048x1024 -> 1024x2048
//  [12288,14336)  zero d_out (8 MB) for the out_proj atomicAdd epilogue
// ---------------------------------------------------------------------------
__device__ __forceinline__ void cvt_ew_body(const float* __restrict__ s,
                                            unsigned short* __restrict__ d,
                                            int blk, int tid) {
  int i = blk * 256 + tid;
  float4 v = ((const float4*)s)[i];
  ushort4 o;
  o.x = f2bf(v.x); o.y = f2bf(v.y); o.z = f2bf(v.z); o.w = f2bf(v.w);
  ((ushort4*)d)[i] = o;
}

__device__ __forceinline__ void cvt_tr_body(const float* __restrict__ s,
                                            unsigned short* __restrict__ d,
                                            int R, int C, int c0, int r0,
                                            int tid, float (*T)[33]) {
#pragma unroll
  for (int i = 0; i < 4; ++i) {
    int e = tid + i * 256;
    int r = e >> 5, c = e & 31;
    T[r][c] = s[(size_t)(r0 + r) * C + c0 + c];
  }
  __syncthreads();
#pragma unroll
  for (int i = 0; i < 4; ++i) {
    int e = tid + i * 256;
    int c = e >> 5, r = e & 31;
    d[(size_t)(c0 + c) * R + r0 + r] = f2bf(T[r][c]);
  }
}

__global__ __launch_bounds__(256) void cvt_all(
    const float* __restrict__ x, const float* __restrict__ w_in,
    const float* __restrict__ dt_w, const float* __restrict__ out_w,
    unsigned short* __restrict__ XB, unsigned short* __restrict__ WINB,
    unsigned short* __restrict__ DTWB, unsigned short* __restrict__ OWB,
    float* __restrict__ out_zero) {
  __shared__ float T[32][33];
  const int bid = blockIdx.x;
  const int tid = threadIdx.x;
  if (bid < 2048) {
    cvt_ew_body(x, XB, bid, tid);
  } else if (bid < 6144) {
    int t = bid - 2048;
    cvt_tr_body(w_in, WINB, 1024, 4096, (t & 127) * 32, (t >> 7) * 32, tid, T);
  } else if (bid < 10240) {
    cvt_ew_body(dt_w, DTWB, bid - 6144, tid);
  } else if (bid < 12288) {
    int t = bid - 10240;
    cvt_tr_body(out_w, OWB, 2048, 1024, (t & 31) * 32, (t >> 5) * 32, tid, T);
  } else {
    int i = (bid - 12288) * 256 + tid;
    ((float4*)out_zero)[i] = make_float4(0.f, 0.f, 0.f, 0.f);
  }
}

// ---------------------------------------------------------------------------
// bf16 MFMA GEMM (NT), 512 threads, BM=128 x BN=128, BK=64 (best measured —
// R10/R12). 8 waves: wave w -> rows (w>>2)*64, cols (w&3)*32; each wave 4x2
// MFMAs of 16x16x32. LDS 32 KB, 2-barrier loop. Static XCD swizzle
// (gridDim.y==16). Split-K via gridDim.z.
// Epilogue modes: 1 = bf16 col<N1 -> C1 else C2  [in_proj u|res]
//                 2 = softplus(v+bias[col]) bf16 [dt_proj]
//                 3 = fp32 atomicAdd into C1     [out_proj split-K, C1 zeroed]
// NOTE (R8/R11): NO inter-block coordination inside kernels — queues and
// grid.sync cost 100+ µs on 8 non-coherent XCDs. Launches are the sync
// primitive. One-shot epilogue atomics (mode 3) are fine.
// ---------------------------------------------------------------------------
__global__ __launch_bounds__(512) void mfma_gemm_nt(
    const unsigned short* __restrict__ A, int lda,
    const unsigned short* __restrict__ Bt, int ldb,
    void* __restrict__ C1v, int ld1,
    void* __restrict__ C2v, int ld2, int N1,
    const float* __restrict__ bias,
    int KS, int mode) {
  __shared__ unsigned short As[8 * 128 * 8];  // 16 KB [kc][row][8]
  __shared__ unsigned short Bs[8 * 128 * 8];  // 16 KB
  const int tid  = threadIdx.x;
  const int wave = tid >> 6;        // 0..7
  const int lane = tid & 63;
  const int linear = blockIdx.y * gridDim.x + blockIdx.x;
  const int xcd = linear & 7;
  const int pos = linear >> 3;
  const int row0 = (xcd * 2 + (pos & 1)) * 128;   // 16 M-panels
  const int col0 = (pos >> 1) * 128;
  const int wm0 = (wave >> 2) * 64;
  const int wn0 = (wave & 3) * 32;
  const int kb = blockIdx.z * KS;

  f32x4 acc[4][2];
#pragma unroll
  for (int i = 0; i < 4; ++i)
#pragma unroll
    for (int j = 0; j < 2; ++j) acc[i][j] = (f32x4){0.f, 0.f, 0.f, 0.f};

  const int lkc = lane >> 4, li = lane & 15;
  for (int k0 = kb; k0 < kb + KS; k0 += 64) {
#pragma unroll
    for (int it = 0; it < 2; ++it) {
      int s = it * 512 + tid;        // 0..1023 A slots (16B each)
      int kc = s >> 7, r = s & 127;
      __builtin_amdgcn_global_load_lds(
          (const __attribute__((address_space(1))) void*)(A + (size_t)(row0 + r) * lda + k0 + kc * 8),
          (__attribute__((address_space(3))) void*)(&As[s * 8]), 16, 0, 0);
    }
#pragma unroll
    for (int it = 0; it < 2; ++it) {
      int s = it * 512 + tid;        // 0..1023 B slots
      int kc = s >> 7, r = s & 127;
      __builtin_amdgcn_global_load_lds(
          (const __attribute__((address_space(1))) void*)(Bt + (size_t)(col0 + r) * ldb + k0 + kc * 8),
          (__attribute__((address_space(3))) void*)(&Bs[s * 8]), 16, 0, 0);
    }
    __syncthreads();
#pragma unroll
    for (int half = 0; half < 2; ++half) {
      bf16x8 af[4], bfr[2];
#pragma unroll
      for (int mt = 0; mt < 4; ++mt)
        af[mt] = *(const bf16x8*)&As[((half * 4 + lkc) * 128 + wm0 + mt * 16 + li) * 8];
#pragma unroll
      for (int nt = 0; nt < 2; ++nt)
        bfr[nt] = *(const bf16x8*)&Bs[((half * 4 + lkc) * 128 + wn0 + nt * 16 + li) * 8];
#pragma unroll
      for (int mt = 0; mt < 4; ++mt)
#pragma unroll
        for (int nt = 0; nt < 2; ++nt)
          acc[mt][nt] = __builtin_amdgcn_mfma_f32_16x16x32_bf16(
              af[mt], bfr[nt], acc[mt][nt], 0, 0, 0);
    }
    __syncthreads();
  }
  // C/D layout: col=lane&15, row=(lane>>4)*4+reg (m89-verified)
  const int lq = lane >> 4;
#pragma unroll
  for (int mt = 0; mt < 4; ++mt) {
    int gm0 = row0 + wm0 + mt * 16 + lq * 4;
#pragma unroll
    for (int nt = 0; nt < 2; ++nt) {
      int gn = col0 + wn0 + nt * 16 + li;
      if (mode == 1) {
        if (gn < N1) {
          unsigned short* C1 = (unsigned short*)C1v;
#pragma unroll
          for (int r = 0; r < 4; ++r)
            C1[(size_t)(gm0 + r) * ld1 + gn] = f2bf(acc[mt][nt][r]);
        } else {
          unsigned short* C2 = (unsigned short*)C2v;
#pragma unroll
          for (int r = 0; r < 4; ++r)
            C2[(size_t)(gm0 + r) * ld2 + gn - N1] = f2bf(acc[mt][nt][r]);
        }
      } else if (mode == 2) {  // softplus(v + bias[col]) -> bf16
        unsigned short* C1 = (unsigned short*)C1v;
        float bb = bias[gn];
#pragma unroll
        for (int r = 0; r < 4; ++r) {
          float v = acc[mt][nt][r] + bb;
          v = (v > 20.f) ? v : __logf(1.f + __expf(v));
          C1[(size_t)(gm0 + r) * ld1 + gn] = f2bf(v);
        }
      } else {  // mode 3: fp32 atomicAdd (C1 pre-zeroed in cvt_all)
        float* C1 = (float*)C1v;
#pragma unroll
        for (int r = 0; r < 4; ++r)
          atomicAdd(&C1[(size_t)(gm0 + r) * ld1 + gn], acc[mt][nt][r]);
      }
    }
  }
}

// ---------------------------------------------------------------------------
// Fused depthwise conv(4)+SiLU + x_proj partial (R11-proven). Block (ks, rt):
// U for rows [rt*64,+64) x d [ks*256,+256), stage in LDS, write UB once,
// then accumulate x_proj K-slice partial C[64][32] into XPART.
// ---------------------------------------------------------------------------
__global__ __launch_bounds__(256) void conv_xproj(
    const unsigned short* __restrict__ UPREB, const float* __restrict__ cw,
    const float* __restrict__ cb, const float* __restrict__ W,
    unsigned short* __restrict__ UB, float* __restrict__ XPART) {
  const int ks = blockIdx.x;        // 0..7
  const int rt = blockIdx.y;        // 0..31
  const int row0 = rt * 64;
  const int kbase = ks * 256;
  __shared__ unsigned short sU[64][256];  // 32 KB
  __shared__ float Bv[256 * 32];          // 32 KB
  const int tid = threadIdx.x;

  for (int i = tid; i < 256 * 32; i += 256)
    Bv[i] = W[(size_t)(kbase + (i >> 5)) * 32 + (i & 31)];

  {
    const int d = kbase + tid;
    const float w0 = cw[d * DCONV + 0], w1 = cw[d * DCONV + 1];
    const float w2 = cw[d * DCONV + 2], w3 = cw[d * DCONV + 3];
    const float bias = cb[d];
    float x0, x1, x2;
    if ((row0 & (LSEQ - 1)) == 0) {
      x0 = x1 = x2 = 0.f;
    } else {
      x0 = bf2f(UPREB[(size_t)(row0 - 3) * DINNER + d]);
      x1 = bf2f(UPREB[(size_t)(row0 - 2) * DINNER + d]);
      x2 = bf2f(UPREB[(size_t)(row0 - 1) * DINNER + d]);
    }
    for (int r = 0; r < 64; ++r) {
      float x3 = bf2f(UPREB[(size_t)(row0 + r) * DINNER + d]);
      float a = bias + x0 * w0 + x1 * w1 + x2 * w2 + x3 * w3;
      float u = a / (1.f + __expf(-a));
      unsigned short ub = f2bf(u);
      sU[r][tid] = ub;
      UB[(size_t)(row0 + r) * DINNER + d] = ub;
      x0 = x1; x1 = x2; x2 = x3;
    }
  }
  __syncthreads();

  const int col = tid & 31, rg = tid >> 5;
  float acc[8] = {};
  for (int k = 0; k < 256; k += 2) {
    float b0 = Bv[k * 32 + col], b1 = Bv[(k + 1) * 32 + col];
#pragma unroll
    for (int rr = 0; rr < 8; ++rr) {
      ushort2 uv = *(const ushort2*)&sU[rg * 8 + rr][k];
      acc[rr] += bf2f(uv.x) * b0 + bf2f(uv.y) * b1;
    }
  }
#pragma unroll
  for (int rr = 0; rr < 8; ++rr)
    XPART[(size_t)ks * NROWS * 32 + (size_t)(row0 + rg * 8 + rr) * 32 + col] = acc[rr];
}

// ---------------------------------------------------------------------------
// Scan pass 1 + inline x_proj reduce. Reduces XPART's 8 K-slices into the
// LDS B-buffer directly (same ks=0..7 order as the old xproj_reduce — bit-
// identical numerics); the d-group-0 block of each chunk also writes the full
// reduced BC (B|C) to BCb for scan_pass2. Kills the xproj_reduce dispatch.
// ---------------------------------------------------------------------------
__global__ __launch_bounds__(256) void scan_pass1(
    const unsigned short* __restrict__ DELTAB, const unsigned short* __restrict__ UB,
    const float* __restrict__ XPART, float* __restrict__ BCb,
    const float* __restrict__ A_log,
    float* __restrict__ PBUF, float* __restrict__ HBUF) {
  const int bx = blockIdx.x;
  const int b = bx >> 8;
  const int c = (bx >> 3) & (NCHUNK - 1);
  const int d = ((bx & 7) << 8) + threadIdx.x;
  const int l0 = c * LCHUNK;
  __shared__ float sB[LCHUNK * DSTATE];
  // reduce B-part (cols 0..15) for this chunk from XPART
#pragma unroll
  for (int i = 0; i < 2; ++i) {
    int e = threadIdx.x + i * 256;       // 0..511 = 32 rows x 16 cols
    int row = e >> 4, col = e & 15;
    size_t base = (size_t)(b * LSEQ + l0 + row) * 32 + col;
    float s = 0.f;
#pragma unroll
    for (int ks = 0; ks < 8; ++ks) s += XPART[(size_t)ks * NROWS * 32 + base];
    sB[e] = s;
  }
  // d-group 0 also publishes the full reduced BC for scan_pass2
  if ((bx & 7) == 0) {
#pragma unroll
    for (int i = 0; i < 4; ++i) {
      int e = threadIdx.x + i * 256;     // 0..1023 = 32 rows x 32 cols
      int row = e >> 5, col = e & 31;
      size_t base = (size_t)(b * LSEQ + l0 + row) * 32 + col;
      float s = 0.f;
#pragma unroll
      for (int ks = 0; ks < 8; ++ks) s += XPART[(size_t)ks * NROWS * 32 + base];
      BCb[base] = s;
    }
  }
  float Avv[DSTATE];
#pragma unroll
  for (int n = 0; n < DSTATE; ++n) Avv[n] = -__expf(A_log[d * DSTATE + n]);
  float h[DSTATE], P[DSTATE];
#pragma unroll
  for (int n = 0; n < DSTATE; ++n) { h[n] = 0.f; P[n] = 1.f; }
  __syncthreads();
  for (int lc = 0; lc < LCHUNK; ++lc) {
    size_t off = ((size_t)(b * LSEQ + l0 + lc)) * DINNER + d;
    float delta = bf2f(DELTAB[off]);
    float du = delta * bf2f(UB[off]);
#pragma unroll
    for (int n = 0; n < DSTATE; ++n) {
      float dA = __expf(delta * Avv[n]);
      P[n] *= dA;
      h[n] = dA * h[n] + du * sB[lc * DSTATE + n];
    }
  }
  size_t base = ((size_t)(b * NCHUNK + c)) * DSTATE * DINNER + d;
#pragma unroll
  for (int n = 0; n < DSTATE; ++n) {
    PBUF[base + (size_t)n * DINNER] = P[n];
    HBUF[base + (size_t)n * DINNER] = h[n];
  }
}

// ---------------------------------------------------------------------------
// Scan combine: sequential prefix across 32 chunks per (b,n,d).
// ---------------------------------------------------------------------------
__global__ __launch_bounds__(256) void scan_combine(
    const float* __restrict__ PBUF, float* __restrict__ HBUF) {
  const int bx = blockIdx.x;
  const int b = bx >> 7;
  const int n = (bx >> 3) & (DSTATE - 1);
  const int d = ((bx & 7) << 8) + threadIdx.x;
  float h = 0.f;
  for (int c = 0; c < NCHUNK; ++c) {
    size_t idx = (((size_t)(b * NCHUNK + c)) * DSTATE + n) * DINNER + d;
    float p = PBUF[idx];
    float hl = HBUF[idx];
    HBUF[idx] = h;
    h = p * h + hl;
  }
}

// ---------------------------------------------------------------------------
// Scan pass 2: rescan from incoming state; y = C.h + u*D, gate silu(res),
// emit bf16 Y.
// ---------------------------------------------------------------------------
__global__ __launch_bounds__(256) void scan_pass2(
    const unsigned short* __restrict__ DELTAB, const unsigned short* __restrict__ UB,
    const float* __restrict__ BC, const float* __restrict__ HBUF,
    const float* __restrict__ A_log, const float* __restrict__ D_param,
    const unsigned short* __restrict__ RESB, unsigned short* __restrict__ YB) {
  const int bx = blockIdx.x;
  const int b = bx >> 8;
  const int c = (bx >> 3) & (NCHUNK - 1);
  const int d = ((bx & 7) << 8) + threadIdx.x;
  const int l0 = c * LCHUNK;
  __shared__ float sBC[LCHUNK * 32];
#pragma unroll
  for (int i = 0; i < 4; ++i) {
    int e = threadIdx.x + i * 256;
    sBC[e] = BC[((size_t)(b * LSEQ + l0 + (e >> 5))) * 32 + (e & 31)];
  }
  float Avv[DSTATE];
#pragma unroll
  for (int n = 0; n < DSTATE; ++n) Avv[n] = -__expf(A_log[d * DSTATE + n]);
  const float Dp = D_param[d];
  float h[DSTATE];
  size_t base = ((size_t)(b * NCHUNK + c)) * DSTATE * DINNER + d;
#pragma unroll
  for (int n = 0; n < DSTATE; ++n) h[n] = HBUF[base + (size_t)n * DINNER];
  __syncthreads();
  for (int lc = 0; lc < LCHUNK; ++lc) {
    size_t off = ((size_t)(b * LSEQ + l0 + lc)) * DINNER + d;
    float delta = bf2f(DELTAB[off]);
    float uu = bf2f(UB[off]);
    float du = delta * uu;
    float y = 0.f;
#pragma unroll
    for (int n = 0; n < DSTATE; ++n) {
      float dA = __expf(delta * Avv[n]);
      h[n] = dA * h[n] + du * sBC[lc * 32 + n];
      y += h[n] * sBC[lc * 32 + 16 + n];
    }
    y += uu * Dp;
    float r = bf2f(RESB[off]);
    YB[off] = f2bf(y * (r / (1.f + __expf(-r))));
  }
}

// ---------------------------------------------------------------------------
extern "C" void kernel_launch(void* const* d_in, const int* in_sizes, int n_in,
                              void* d_out, int out_size, void* d_ws, size_t ws_size,
                              hipStream_t stream) {
  const float* x       = (const float*)d_in[0];
  const float* w_in    = (const float*)d_in[1];
  const float* conv_w  = (const float*)d_in[2];
  const float* conv_b  = (const float*)d_in[3];
  const float* xproj_w = (const float*)d_in[4];
  const float* dt_w    = (const float*)d_in[5];
  const float* dt_b    = (const float*)d_in[6];
  const float* A_log   = (const float*)d_in[7];
  const float* D_par   = (const float*)d_in[8];
  const float* out_w   = (const float*)d_in[9];
  float* out = (float*)d_out;

  char* ws = (char*)d_ws;
  const size_t MB = 1024 * 1024;
  // bf16 activation buffers
  unsigned short* UPREB  = (unsigned short*)(ws + 0 * MB);   // 8 MB (dead after conv_xproj)
  unsigned short* RESB   = (unsigned short*)(ws + 8 * MB);   // 8 MB (dead after scan)
  unsigned short* UB     = (unsigned short*)(ws + 16 * MB);  // 8 MB
  unsigned short* DELTAB = (unsigned short*)(ws + 24 * MB);  // 8 MB
  unsigned short* YB     = (unsigned short*)(ws + 32 * MB);  // 8 MB
  unsigned short* XB     = (unsigned short*)(ws + 40 * MB);  // 4 MB (dead after in_proj)
  unsigned short* WINB   = (unsigned short*)(ws + 44 * MB);  // 8 MB (dead after in_proj)
  unsigned short* DTWB   = (unsigned short*)(ws + 52 * MB);  // 8 MB (dead after dt_proj)
  unsigned short* OWB    = (unsigned short*)(ws + 60 * MB);  // 4 MB (live to end)
  // overlays (first written strictly after underlying buffer dies)
  float* PBUF  = (float*)(ws + 0 * MB);                 // 8 MB over UPREB (w: pass1)
  float* HBUF  = (float*)(ws + 40 * MB);                // 8 MB over XB+WINB[0:4] (w: pass1)
  float* BCb   = (float*)(ws + 48 * MB);                // 256 KB over WINB[4:] (w: pass1)
  float* XPART = (float*)(ws + 48 * MB + 512 * 1024);   // 2 MB over WINB[4:] (w: conv_xproj)
  // footprint: 64 MB

  // input conversions + d_out zeroing (8 dispatches total this launch)
  cvt_all<<<dim3(14336), dim3(256), 0, stream>>>(
      x, w_in, dt_w, out_w, XB, WINB, DTWB, OWB, out);
  // in_proj: XB(2048x1024) x WINB(4096x1024)^T -> UPREB | RESB bf16
  mfma_gemm_nt<<<dim3(2 * DINNER / 128, NROWS / 128, 1), dim3(512), 0, stream>>>(
      XB, DMODEL, WINB, DMODEL, UPREB, DINNER, RESB, DINNER, DINNER,
      nullptr, DMODEL, 1);
  // fused conv+silu+x_proj partial -> UB, XPART
  conv_xproj<<<dim3(8, NROWS / 64), dim3(256), 0, stream>>>(
      UPREB, conv_w, conv_b, xproj_w, UB, XPART);
  // dt_proj: UB x DTWB^T, softplus(+dt_b) epilogue -> DELTAB bf16
  mfma_gemm_nt<<<dim3(DINNER / 128, NROWS / 128, 1), dim3(512), 0, stream>>>(
      UB, DINNER, DTWB, DINNER, DELTAB, DINNER, nullptr, 0, DINNER,
      dt_b, DINNER, 2);
  // chunked selective scan (pass1 folds the x_proj reduce; 3 dispatches —
  // launches ARE the sync primitive on this chip)
  scan_pass1<<<dim3(BATCH * NCHUNK * (DINNER / 256)), dim3(256), 0, stream>>>(
      DELTAB, UB, XPART, BCb, A_log, PBUF, HBUF);
  scan_combine<<<dim3(BATCH * DSTATE * (DINNER / 256)), dim3(256), 0, stream>>>(PBUF, HBUF);
  scan_pass2<<<dim3(BATCH * NCHUNK * (DINNER / 256)), dim3(256), 0, stream>>>(
      DELTAB, UB, BCb, HBUF, A_log, D_par, RESB, YB);
  // out_proj: YB(2048x2048) x OWB(1024x2048)^T, split-K=2 atomicAdd -> out
  mfma_gemm_nt<<<dim3(DMODEL / 128, NROWS / 128, 2), dim3(512), 0, stream>>>(
      YB, DINNER, OWB, DINNER, out, DMODEL, nullptr, 0, DMODEL,
      nullptr, DINNER / 2, 3);
}

// Round 14
// 323.148 us; speedup vs baseline: 1.8937x; 1.0130x over previous
//
#include <hip/hip_runtime.h>
#include <math.h>

// Problem constants
#define BATCH   2
#define LSEQ    1024
#define DMODEL  1024
#define DSTATE  16
#define DCONV   4
#define DINNER  2048
#define NROWS   (BATCH * LSEQ)   // 2048

#define LCHUNK  32
#define NCHUNK  32

typedef short  bf16x8 __attribute__((ext_vector_type(8)));
typedef float  f32x4  __attribute__((ext_vector_type(4)));

__device__ __forceinline__ unsigned short f2bf(float f) {
  unsigned int u = __builtin_bit_cast(unsigned int, f);
  u = (u + 0x7fffu + ((u >> 16) & 1u)) >> 16;   // RNE
  return (unsigned short)u;
}
__device__ __forceinline__ float bf2f(unsigned short h) {
  return __builtin_bit_cast(float, (unsigned int)h << 16);
}

// ---------------------------------------------------------------------------
// Fused input conversion + d_out zeroing (R13-proven). 5 regions.
// ---------------------------------------------------------------------------
__device__ __forceinline__ void cvt_ew_body(const float* __restrict__ s,
                                            unsigned short* __restrict__ d,
                                            int blk, int tid) {
  int i = blk * 256 + tid;
  float4 v = ((const float4*)s)[i];
  ushort4 o;
  o.x = f2bf(v.x); o.y = f2bf(v.y); o.z = f2bf(v.z); o.w = f2bf(v.w);
  ((ushort4*)d)[i] = o;
}

__device__ __forceinline__ void cvt_tr_body(const float* __restrict__ s,
                                            unsigned short* __restrict__ d,
                                            int R, int C, int c0, int r0,
                                            int tid, float (*T)[33]) {
#pragma unroll
  for (int i = 0; i < 4; ++i) {
    int e = tid + i * 256;
    int r = e >> 5, c = e & 31;
    T[r][c] = s[(size_t)(r0 + r) * C + c0 + c];
  }
  __syncthreads();
#pragma unroll
  for (int i = 0; i < 4; ++i) {
    int e = tid + i * 256;
    int c = e >> 5, r = e & 31;
    d[(size_t)(c0 + c) * R + r0 + r] = f2bf(T[r][c]);
  }
}

__global__ __launch_bounds__(256) void cvt_all(
    const float* __restrict__ x, const float* __restrict__ w_in,
    const float* __restrict__ dt_w, const float* __restrict__ out_w,
    unsigned short* __restrict__ XB, unsigned short* __restrict__ WINB,
    unsigned short* __restrict__ DTWB, unsigned short* __restrict__ OWB,
    float* __restrict__ out_zero) {
  __shared__ float T[32][33];
  const int bid = blockIdx.x;
  const int tid = threadIdx.x;
  if (bid < 2048) {
    cvt_ew_body(x, XB, bid, tid);
  } else if (bid < 6144) {
    int t = bid - 2048;
    cvt_tr_body(w_in, WINB, 1024, 4096, (t & 127) * 32, (t >> 7) * 32, tid, T);
  } else if (bid < 10240) {
    cvt_ew_body(dt_w, DTWB, bid - 6144, tid);
  } else if (bid < 12288) {
    int t = bid - 10240;
    cvt_tr_body(out_w, OWB, 2048, 1024, (t & 31) * 32, (t >> 5) * 32, tid, T);
  } else {
    int i = (bid - 12288) * 256 + tid;
    ((float4*)out_zero)[i] = make_float4(0.f, 0.f, 0.f, 0.f);
  }
}

// ---------------------------------------------------------------------------
// bf16 MFMA GEMM (NT), 512 threads, BM=128 x BN (template: 128 or 256),
// BK=64. 8 waves as 2(row)x4(col): wave w -> rows (w>>2)*64, cols
// (w&3)*(BN/4); each wave 4 x (BN/64) MFMAs of 16x16x32. LDS 16+BN/8 KB.
// BN=256 cuts staging traffic 25% for wide-N GEMMs (in_proj).
// Static XCD swizzle (gridDim.y==16). Split-K via gridDim.z.
// Epilogue modes: 1 = bf16 col<N1 -> C1 else C2  [in_proj u|res]
//                 2 = softplus(v+bias[col]) bf16 [dt_proj]
//                 3 = fp32 atomicAdd into C1     [out_proj split-K, C1 zeroed]
// NOTE (R8/R11): NO inter-block coordination inside kernels — queues and
// grid.sync cost 100+ µs on 8 non-coherent XCDs. Launches are the sync
// primitive. One-shot epilogue atomics (mode 3) are fine.
// ---------------------------------------------------------------------------
template <int BN>
__global__ __launch_bounds__(512) void mfma_gemm_nt(
    const unsigned short* __restrict__ A, int lda,
    const unsigned short* __restrict__ Bt, int ldb,
    void* __restrict__ C1v, int ld1,
    void* __restrict__ C2v, int ld2, int N1,
    const float* __restrict__ bias,
    int KS, int mode) {
  constexpr int NT = BN / 64;                 // col MFMA tiles per wave
  __shared__ unsigned short As[8 * 128 * 8];  // 16 KB [kc][row][8]
  __shared__ unsigned short Bs[8 * BN * 8];   // BN/8 KB
  const int tid  = threadIdx.x;
  const int wave = tid >> 6;        // 0..7
  const int lane = tid & 63;
  const int linear = blockIdx.y * gridDim.x + blockIdx.x;
  const int xcd = linear & 7;
  const int pos = linear >> 3;
  const int row0 = (xcd * 2 + (pos & 1)) * 128;   // 16 M-panels
  const int col0 = (pos >> 1) * BN;
  const int wm0 = (wave >> 2) * 64;
  const int wn0 = (wave & 3) * (BN / 4);
  const int kb = blockIdx.z * KS;

  f32x4 acc[4][NT];
#pragma unroll
  for (int i = 0; i < 4; ++i)
#pragma unroll
    for (int j = 0; j < NT; ++j) acc[i][j] = (f32x4){0.f, 0.f, 0.f, 0.f};

  const int lkc = lane >> 4, li = lane & 15;
  for (int k0 = kb; k0 < kb + KS; k0 += 64) {
#pragma unroll
    for (int it = 0; it < 2; ++it) {
      int s = it * 512 + tid;        // 0..1023 A slots (16B each)
      int kc = s >> 7, r = s & 127;
      __builtin_amdgcn_global_load_lds(
          (const __attribute__((address_space(1))) void*)(A + (size_t)(row0 + r) * lda + k0 + kc * 8),
          (__attribute__((address_space(3))) void*)(&As[s * 8]), 16, 0, 0);
    }
#pragma unroll
    for (int it = 0; it < BN / 64; ++it) {
      int s = it * 512 + tid;        // 0..8*BN-1 B slots
      int kc = s / BN, r = s % BN;   // BN is pow2 -> shifts
      __builtin_amdgcn_global_load_lds(
          (const __attribute__((address_space(1))) void*)(Bt + (size_t)(col0 + r) * ldb + k0 + kc * 8),
          (__attribute__((address_space(3))) void*)(&Bs[s * 8]), 16, 0, 0);
    }
    __syncthreads();
#pragma unroll
    for (int half = 0; half < 2; ++half) {
      bf16x8 af[4], bfr[NT];
#pragma unroll
      for (int mt = 0; mt < 4; ++mt)
        af[mt] = *(const bf16x8*)&As[((half * 4 + lkc) * 128 + wm0 + mt * 16 + li) * 8];
#pragma unroll
      for (int nt = 0; nt < NT; ++nt)
        bfr[nt] = *(const bf16x8*)&Bs[((half * 4 + lkc) * BN + wn0 + nt * 16 + li) * 8];
#pragma unroll
      for (int mt = 0; mt < 4; ++mt)
#pragma unroll
        for (int nt = 0; nt < NT; ++nt)
          acc[mt][nt] = __builtin_amdgcn_mfma_f32_16x16x32_bf16(
              af[mt], bfr[nt], acc[mt][nt], 0, 0, 0);
    }
    __syncthreads();
  }
  // C/D layout: col=lane&15, row=(lane>>4)*4+reg (m89-verified)
  const int lq = lane >> 4;
#pragma unroll
  for (int mt = 0; mt < 4; ++mt) {
    int gm0 = row0 + wm0 + mt * 16 + lq * 4;
#pragma unroll
    for (int nt = 0; nt < NT; ++nt) {
      int gn = col0 + wn0 + nt * 16 + li;
      if (mode == 1) {
        if (gn < N1) {
          unsigned short* C1 = (unsigned short*)C1v;
#pragma unroll
          for (int r = 0; r < 4; ++r)
            C1[(size_t)(gm0 + r) * ld1 + gn] = f2bf(acc[mt][nt][r]);
        } else {
          unsigned short* C2 = (unsigned short*)C2v;
#pragma unroll
          for (int r = 0; r < 4; ++r)
            C2[(size_t)(gm0 + r) * ld2 + gn - N1] = f2bf(acc[mt][nt][r]);
        }
      } else if (mode == 2) {  // softplus(v + bias[col]) -> bf16
        unsigned short* C1 = (unsigned short*)C1v;
        float bb = bias[gn];
#pragma unroll
        for (int r = 0; r < 4; ++r) {
          float v = acc[mt][nt][r] + bb;
          v = (v > 20.f) ? v : __logf(1.f + __expf(v));
          C1[(size_t)(gm0 + r) * ld1 + gn] = f2bf(v);
        }
      } else {  // mode 3: fp32 atomicAdd (C1 pre-zeroed in cvt_all)
        float* C1 = (float*)C1v;
#pragma unroll
        for (int r = 0; r < 4; ++r)
          atomicAdd(&C1[(size_t)(gm0 + r) * ld1 + gn], acc[mt][nt][r]);
      }
    }
  }
}

// ---------------------------------------------------------------------------
// Fused depthwise conv(4)+SiLU + x_proj partial — 16-row tiles for 4x the
// blocks (1024 = 4 blocks/CU vs R13's 256 = 1/CU). Halo rows are read from
// UPREB (written fully by in_proj); batch boundary (row0 % LSEQ == 0) zeroes
// the history. LDS: sU 8 KB + Bv 32 KB = 40 KB.
// ---------------------------------------------------------------------------
__global__ __launch_bounds__(256) void conv_xproj(
    const unsigned short* __restrict__ UPREB, const float* __restrict__ cw,
    const float* __restrict__ cb, const float* __restrict__ W,
    unsigned short* __restrict__ UB, float* __restrict__ XPART) {
  const int ks = blockIdx.x;        // 0..7
  const int rt = blockIdx.y;        // 0..127
  const int row0 = rt * 16;
  const int kbase = ks * 256;
  __shared__ unsigned short sU[16][256];  // 8 KB
  __shared__ float Bv[256 * 32];          // 32 KB
  const int tid = threadIdx.x;

  for (int i = tid; i < 256 * 32; i += 256)
    Bv[i] = W[(size_t)(kbase + (i >> 5)) * 32 + (i & 31)];

  {
    const int d = kbase + tid;
    const float w0 = cw[d * DCONV + 0], w1 = cw[d * DCONV + 1];
    const float w2 = cw[d * DCONV + 2], w3 = cw[d * DCONV + 3];
    const float bias = cb[d];
    float x0, x1, x2;
    if ((row0 & (LSEQ - 1)) == 0) {
      x0 = x1 = x2 = 0.f;
    } else {
      x0 = bf2f(UPREB[(size_t)(row0 - 3) * DINNER + d]);
      x1 = bf2f(UPREB[(size_t)(row0 - 2) * DINNER + d]);
      x2 = bf2f(UPREB[(size_t)(row0 - 1) * DINNER + d]);
    }
    for (int r = 0; r < 16; ++r) {
      float x3 = bf2f(UPREB[(size_t)(row0 + r) * DINNER + d]);
      float a = bias + x0 * w0 + x1 * w1 + x2 * w2 + x3 * w3;
      float u = a / (1.f + __expf(-a));
      unsigned short ub = f2bf(u);
      sU[r][tid] = ub;
      UB[(size_t)(row0 + r) * DINNER + d] = ub;
      x0 = x1; x1 = x2; x2 = x3;
    }
  }
  __syncthreads();

  // x_proj partial: C[16][32] = sU[16][256] @ W[256][32]; 8 groups x 2 rows
  const int col = tid & 31, rg = tid >> 5;
  float acc[2] = {};
  for (int k = 0; k < 256; k += 2) {
    float b0 = Bv[k * 32 + col], b1 = Bv[(k + 1) * 32 + col];
#pragma unroll
    for (int rr = 0; rr < 2; ++rr) {
      ushort2 uv = *(const ushort2*)&sU[rg * 2 + rr][k];
      acc[rr] += bf2f(uv.x) * b0 + bf2f(uv.y) * b1;
    }
  }
#pragma unroll
  for (int rr = 0; rr < 2; ++rr)
    XPART[(size_t)ks * NROWS * 32 + (size_t)(row0 + rg * 2 + rr) * 32 + col] = acc[rr];
}

// ---------------------------------------------------------------------------
// Scan pass 1 + inline x_proj reduce (R13-proven).
// ---------------------------------------------------------------------------
__global__ __launch_bounds__(256) void scan_pass1(
    const unsigned short* __restrict__ DELTAB, const unsigned short* __restrict__ UB,
    const float* __restrict__ XPART, float* __restrict__ BCb,
    const float* __restrict__ A_log,
    float* __restrict__ PBUF, float* __restrict__ HBUF) {
  const int bx = blockIdx.x;
  const int b = bx >> 8;
  const int c = (bx >> 3) & (NCHUNK - 1);
  const int d = ((bx & 7) << 8) + threadIdx.x;
  const int l0 = c * LCHUNK;
  __shared__ float sB[LCHUNK * DSTATE];
#pragma unroll
  for (int i = 0; i < 2; ++i) {
    int e = threadIdx.x + i * 256;       // 32 rows x 16 cols
    int row = e >> 4, col = e & 15;
    size_t base = (size_t)(b * LSEQ + l0 + row) * 32 + col;
    float s = 0.f;
#pragma unroll
    for (int ks = 0; ks < 8; ++ks) s += XPART[(size_t)ks * NROWS * 32 + base];
    sB[e] = s;
  }
  if ((bx & 7) == 0) {
#pragma unroll
    for (int i = 0; i < 4; ++i) {
      int e = threadIdx.x + i * 256;     // 32 rows x 32 cols
      int row = e >> 5, col = e & 31;
      size_t base = (size_t)(b * LSEQ + l0 + row) * 32 + col;
      float s = 0.f;
#pragma unroll
      for (int ks = 0; ks < 8; ++ks) s += XPART[(size_t)ks * NROWS * 32 + base];
      BCb[base] = s;
    }
  }
  float Avv[DSTATE];
#pragma unroll
  for (int n = 0; n < DSTATE; ++n) Avv[n] = -__expf(A_log[d * DSTATE + n]);
  float h[DSTATE], P[DSTATE];
#pragma unroll
  for (int n = 0; n < DSTATE; ++n) { h[n] = 0.f; P[n] = 1.f; }
  __syncthreads();
  for (int lc = 0; lc < LCHUNK; ++lc) {
    size_t off = ((size_t)(b * LSEQ + l0 + lc)) * DINNER + d;
    float delta = bf2f(DELTAB[off]);
    float du = delta * bf2f(UB[off]);
#pragma unroll
    for (int n = 0; n < DSTATE; ++n) {
      float dA = __expf(delta * Avv[n]);
      P[n] *= dA;
      h[n] = dA * h[n] + du * sB[lc * DSTATE + n];
    }
  }
  size_t base = ((size_t)(b * NCHUNK + c)) * DSTATE * DINNER + d;
#pragma unroll
  for (int n = 0; n < DSTATE; ++n) {
    PBUF[base + (size_t)n * DINNER] = P[n];
    HBUF[base + (size_t)n * DINNER] = h[n];
  }
}

// ---------------------------------------------------------------------------
// Scan combine: sequential prefix across 32 chunks per (b,n,d).
// ---------------------------------------------------------------------------
__global__ __launch_bounds__(256) void scan_combine(
    const float* __restrict__ PBUF, float* __restrict__ HBUF) {
  const int bx = blockIdx.x;
  const int b = bx >> 7;
  const int n = (bx >> 3) & (DSTATE - 1);
  const int d = ((bx & 7) << 8) + threadIdx.x;
  float h = 0.f;
  for (int c = 0; c < NCHUNK; ++c) {
    size_t idx = (((size_t)(b * NCHUNK + c)) * DSTATE + n) * DINNER + d;
    float p = PBUF[idx];
    float hl = HBUF[idx];
    HBUF[idx] = h;
    h = p * h + hl;
  }
}

// ---------------------------------------------------------------------------
// Scan pass 2: rescan from incoming state; y = C.h + u*D, gate silu(res),
// emit bf16 Y.
// ---------------------------------------------------------------------------
__global__ __launch_bounds__(256) void scan_pass2(
    const unsigned short* __restrict__ DELTAB, const unsigned short* __restrict__ UB,
    const float* __restrict__ BC, const float* __restrict__ HBUF,
    const float* __restrict__ A_log, const float* __restrict__ D_param,
    const unsigned short* __restrict__ RESB, unsigned short* __restrict__ YB) {
  const int bx = blockIdx.x;
  const int b = bx >> 8;
  const int c = (bx >> 3) & (NCHUNK - 1);
  const int d = ((bx & 7) << 8) + threadIdx.x;
  const int l0 = c * LCHUNK;
  __shared__ float sBC[LCHUNK * 32];
#pragma unroll
  for (int i = 0; i < 4; ++i) {
    int e = threadIdx.x + i * 256;
    sBC[e] = BC[((size_t)(b * LSEQ + l0 + (e >> 5))) * 32 + (e & 31)];
  }
  float Avv[DSTATE];
#pragma unroll
  for (int n = 0; n < DSTATE; ++n) Avv[n] = -__expf(A_log[d * DSTATE + n]);
  const float Dp = D_param[d];
  float h[DSTATE];
  size_t base = ((size_t)(b * NCHUNK + c)) * DSTATE * DINNER + d;
#pragma unroll
  for (int n = 0; n < DSTATE; ++n) h[n] = HBUF[base + (size_t)n * DINNER];
  __syncthreads();
  for (int lc = 0; lc < LCHUNK; ++lc) {
    size_t off = ((size_t)(b * LSEQ + l0 + lc)) * DINNER + d;
    float delta = bf2f(DELTAB[off]);
    float uu = bf2f(UB[off]);
    float du = delta * uu;
    float y = 0.f;
#pragma unroll
    for (int n = 0; n < DSTATE; ++n) {
      float dA = __expf(delta * Avv[n]);
      h[n] = dA * h[n] + du * sBC[lc * 32 + n];
      y += h[n] * sBC[lc * 32 + 16 + n];
    }
    y += uu * Dp;
    float r = bf2f(RESB[off]);
    YB[off] = f2bf(y * (r / (1.f + __expf(-r))));
  }
}

// ---------------------------------------------------------------------------
extern "C" void kernel_launch(void* const* d_in, const int* in_sizes, int n_in,
                              void* d_out, int out_size, void* d_ws, size_t ws_size,
                              hipStream_t stream) {
  const float* x       = (const float*)d_in[0];
  const float* w_in    = (const float*)d_in[1];
  const float* conv_w  = (const float*)d_in[2];
  const float* conv_b  = (const float*)d_in[3];
  const float* xproj_w = (const float*)d_in[4];
  const float* dt_w    = (const float*)d_in[5];
  const float* dt_b    = (const float*)d_in[6];
  const float* A_log   = (const float*)d_in[7];
  const float* D_par   = (const float*)d_in[8];
  const float* out_w   = (const float*)d_in[9];
  float* out = (float*)d_out;

  char* ws = (char*)d_ws;
  const size_t MB = 1024 * 1024;
  // bf16 activation buffers
  unsigned short* UPREB  = (unsigned short*)(ws + 0 * MB);   // 8 MB (dead after conv_xproj)
  unsigned short* RESB   = (unsigned short*)(ws + 8 * MB);   // 8 MB (dead after scan)
  unsigned short* UB     = (unsigned short*)(ws + 16 * MB);  // 8 MB
  unsigned short* DELTAB = (unsigned short*)(ws + 24 * MB);  // 8 MB
  unsigned short* YB     = (unsigned short*)(ws + 32 * MB);  // 8 MB
  unsigned short* XB     = (unsigned short*)(ws + 40 * MB);  // 4 MB (dead after in_proj)
  unsigned short* WINB   = (unsigned short*)(ws + 44 * MB);  // 8 MB (dead after in_proj)
  unsigned short* DTWB   = (unsigned short*)(ws + 52 * MB);  // 8 MB (dead after dt_proj)
  unsigned short* OWB    = (unsigned short*)(ws + 60 * MB);  // 4 MB (live to end)
  // overlays (first written strictly after underlying buffer dies)
  float* PBUF  = (float*)(ws + 0 * MB);                 // 8 MB over UPREB (w: pass1)
  float* HBUF  = (float*)(ws + 40 * MB);                // 8 MB over XB+WINB[0:4] (w: pass1)
  float* BCb   = (float*)(ws + 48 * MB);                // 256 KB over WINB[4:] (w: pass1)
  float* XPART = (float*)(ws + 48 * MB + 512 * 1024);   // 2 MB over WINB[4:] (w: conv_xproj)
  // footprint: 64 MB

  // input conversions + d_out zeroing
  cvt_all<<<dim3(14336), dim3(256), 0, stream>>>(
      x, w_in, dt_w, out_w, XB, WINB, DTWB, OWB, out);
  // in_proj: XB(2048x1024) x WINB(4096x1024)^T -> UPREB | RESB bf16
  // BN=256: 192 MB staging (0.75x of BN=128), grid 16x16 = 1 block/CU @ 8 waves
  mfma_gemm_nt<256><<<dim3(2 * DINNER / 256, NROWS / 128, 1), dim3(512), 0, stream>>>(
      XB, DMODEL, WINB, DMODEL, UPREB, DINNER, RESB, DINNER, DINNER,
      nullptr, DMODEL, 1);
  // fused conv+silu+x_proj partial -> UB, XPART (16-row tiles, 1024 blocks)
  conv_xproj<<<dim3(8, NROWS / 16), dim3(256), 0, stream>>>(
      UPREB, conv_w, conv_b, xproj_w, UB, XPART);
  // dt_proj: UB x DTWB^T, softplus(+dt_b) epilogue -> DELTAB bf16
  mfma_gemm_nt<128><<<dim3(DINNER / 128, NROWS / 128, 1), dim3(512), 0, stream>>>(
      UB, DINNER, DTWB, DINNER, DELTAB, DINNER, nullptr, 0, DINNER,
      dt_b, DINNER, 2);
  // chunked selective scan (pass1 folds the x_proj reduce)
  scan_pass1<<<dim3(BATCH * NCHUNK * (DINNER / 256)), dim3(256), 0, stream>>>(
      DELTAB, UB, XPART, BCb, A_log, PBUF, HBUF);
  scan_combine<<<dim3(BATCH * DSTATE * (DINNER / 256)), dim3(256), 0, stream>>>(PBUF, HBUF);
  scan_pass2<<<dim3(BATCH * NCHUNK * (DINNER / 256)), dim3(256), 0, stream>>>(
      DELTAB, UB, BCb, HBUF, A_log, D_par, RESB, YB);
  // out_proj: YB(2048x2048) x OWB(1024x2048)^T, split-K=2 atomicAdd -> out
  mfma_gemm_nt<128><<<dim3(DMODEL / 128, NROWS / 128, 2), dim3(512), 0, stream>>>(
      YB, DINNER, OWB, DINNER, out, DMODEL, nullptr, 0, DMODEL,
      nullptr, DINNER / 2, 3);
}